// Round 5
// baseline (219.344 us; speedup 1.0000x reference)
//
#include <hip/hip_runtime.h>

#define HID 64
#define TT  128
#define NROWS 8192
#define NBLK (NROWS / 32)   // 256 blocks x 32 rows (4 waves x 8 rows); 1 block/CU
#define LOG2E 1.44269504088896f

typedef _Float16 half8 __attribute__((ext_vector_type(8)));
typedef float    f32x4 __attribute__((ext_vector_type(4)));

// Row-split GRU: each wave owns 8 rows and the FULL hidden state for them.
// MFMA cols 0-7 = rows, cols 8-15 = replicas; activation deduped by c-half
// (c<8 -> h-tiles 0,1; c>=8 -> tiles 2,3). h round-trips through wave-private
// LDS (no barrier: same-wave DS ordering). Biases ride as feature k=21 == 1.0.
__global__ __launch_bounds__(256, 1) void gru_fused(
    const int* __restrict__ actor_ids, const int* __restrict__ action_ids,
    const int* __restrict__ street_ids, const float* __restrict__ bet,
    const int* __restrict__ mask,
    const float* __restrict__ E_actor, const float* __restrict__ E_action,
    const float* __restrict__ E_street, const float* __restrict__ W_proj,
    const float* __restrict__ b_proj, const float* __restrict__ W_ih,
    const float* __restrict__ b_ih, const float* __restrict__ W_hh,
    const float* __restrict__ b_hh, float* __restrict__ out)
{
    __shared__ __align__(16) union {
        float wfs[192][32];                       // startup: fused W_f (scaled)
        struct {
            int pb[TT][33];                       // ids|bet16, 33-pad
            __align__(16) _Float16 hbuf[4][8][80]; // per-wave h, row stride 160B
        } c;
    } A;
    __shared__ __align__(16) _Float16 embl[144];

    const int tid = threadIdx.x;
    const int w   = tid >> 6;        // wave -> 8 rows
    const int l   = tid & 63;
    const int u   = l >> 4;          // k-slot quad (B) / D-row quad
    const int c   = l & 15;          // MFMA col; row = c&7
    const int cr  = c & 7;
    const bool loT = (c < 8);        // this lane activates h-tiles {0,1} vs {2,3}
    const int g   = blockIdx.x;

    // embedding rows: 0..6 actor, 7..10 action, 11..15 street(+pad), 16 zero
    for (int i = tid; i < 136; i += 256) {
        int r = i >> 3, m = i & 7;
        float v = 0.f;
        if (r < 7)       v = E_actor[r * 8 + m];
        else if (r < 11) v = E_action[(r - 7) * 8 + m];
        else if (r < 16) v = (m < 4) ? E_street[(r - 11) * 4 + m] : 0.f;
        embl[i] = (_Float16)v;
    }

    // ---- startup: fused input weights into LDS; bias folded at k=21 ----
    // W_f[j][m] = sum_k W_ih[j,k]*W_proj[k,m]; wfs[j][21] = b_f (+ b_hh for r,z).
    if (tid < 192) {
        const int j = tid;
        float wf[22];
        #pragma unroll
        for (int m = 0; m < 22; m++) wf[m] = 0.f;
        float bf = b_ih[j];
        for (int k = 0; k < 32; k++) {
            const float wv = W_ih[j * 32 + k];
            bf += wv * b_proj[k];
            #pragma unroll
            for (int m = 0; m < 21; m++) wf[m] += wv * W_proj[k * 21 + m];
        }
        wf[21] = bf + (j < 128 ? b_hh[j] : 0.f);
        const float s = (j < 128) ? LOG2E : 2.f * LOG2E;
        #pragma unroll
        for (int m = 0; m < 22; m++) A.wfs[j][m] = wf[m] * s;
        #pragma unroll
        for (int m = 22; m < 32; m++) A.wfs[j][m] = 0.f;
    }
    __syncthreads();

    // ---- per-lane fragments: Af[12] (x-side), Ah[12][2] (h-side), biasH ----
    // A-layout: A[m=lane&15][k=(lane>>4)*8+pos]; j-tile jt covers j=16jt..16jt+15.
    // Tiles 0-3 = r gates, 4-7 = z, 8-11 = n.
    half8 Af[12], Ah[12][2];
    #pragma unroll
    for (int jt = 0; jt < 12; jt++) {
        const int jr = jt * 16 + c;
        _Float16 v[8];
        #pragma unroll
        for (int m = 0; m < 8; m++) v[m] = (_Float16)A.wfs[jr][u * 8 + m];
        Af[jt] = *(half8*)v;
        const float s = (jt < 8) ? LOG2E : 2.f * LOG2E;
        #pragma unroll
        for (int kt = 0; kt < 2; kt++) {
            _Float16 w8[8];
            #pragma unroll
            for (int m = 0; m < 8; m++)
                w8[m] = (_Float16)(W_hh[jr * HID + kt * 32 + u * 8 + m] * s);
            Ah[jt][kt] = *(half8*)w8;
        }
    }
    f32x4 biasH[4];
    #pragma unroll
    for (int T = 0; T < 4; T++)
        #pragma unroll
        for (int e = 0; e < 4; e++)
            biasH[T][e] = b_hh[128 + 16 * T + 4 * u + e] * (2.f * LOG2E);
    __syncthreads();   // wfs dead; arena becomes pb/hbuf. Last barrier.

    // ---- stage pb + in-wave lengths (wave w stages its own rows 8w..8w+7) ----
    int Lrow;
    {
        const int r32 = tid >> 3, j = tid & 7;
        const int base = (g * 32 + r32) * TT;
        int cnt = 0;
        #pragma unroll
        for (int i = 0; i < 16; i++) {
            const int t = j + 8 * i;
            const int a = actor_ids[base + t], ac = action_ids[base + t];
            const int s = street_ids[base + t];
            const _Float16 f16v = (_Float16)bet[base + t];
            const unsigned fb = (unsigned)*(const unsigned short*)&f16v;
            A.c.pb[t][r32] = (int)(a | (ac << 3) | (s << 5) | (fb << 16));
            cnt += (mask[base + t] != 0);
        }
        cnt += __shfl_xor(cnt, 1);
        cnt += __shfl_xor(cnt, 2);
        cnt += __shfl_xor(cnt, 4);
        Lrow = cnt;                       // lanes 8r..8r+7 hold L(row r32)
    }
    const int Ln = __shfl(Lrow, cr << 3); // L of this lane's row (8w+cr)
    int Lmax = Ln;
    { int o = __shfl_xor(Lmax, 1); Lmax = o > Lmax ? o : Lmax; }
    { int o = __shfl_xor(Lmax, 2); Lmax = o > Lmax ? o : Lmax; }
    { int o = __shfl_xor(Lmax, 4); Lmax = o > Lmax ? o : Lmax; }

    // ---- zero this wave's h slots (each lane owns its write slots) ----
    _Float16* hbW = &A.c.hbuf[w][cr][0];
    const int T0f = loT ? 0 : 32;        // f16 offset of first owned tile
    {
        uint2 z2; z2.x = 0; z2.y = 0;
        *(uint2*)&hbW[T0f + 4 * u] = z2;
        *(uint2*)&hbW[T0f + 16 + 4 * u] = z2;
    }

    const int sh = (u == 1) ? 3 : (u == 2) ? 5 : 0;
    const int mk = (u == 1) ? 3 : (u == 3) ? 0 : 7;
    const int of = (u == 1) ? 7 : (u == 2) ? 11 : (u == 3) ? 16 : 0;
    const bool isu2 = (u == 2);

    const f32x4 zero4 = {0.f, 0.f, 0.f, 0.f};
    float hA[4] = {0.f, 0.f, 0.f, 0.f}, hB[4] = {0.f, 0.f, 0.f, 0.f};

    // prime Bf(0): feature k-slots per u (0:actor 1:action 2:street|bet|1.0 3:zero)
    half8 Bf;
    {
        const int p = A.c.pb[0][8 * w + cr];
        Bf = *(const half8*)&embl[(((p >> sh) & mk) + of) * 8];
        uint4* bu = (uint4*)&Bf;
        bu->z = isu2 ? (((unsigned)p >> 16) | 0x3C000000u) : bu->z;
    }

    for (int t = 0; t < Lmax; t++) {
        // h(t-1) from wave-private LDS (same-wave DS ordering; no barrier)
        const half8 Bh0 = *(const half8*)&hbW[8 * u];
        const half8 Bh1 = *(const half8*)&hbW[32 + 8 * u];

        // x-side: 12 tiles, C=0 (bias rides feature 21)
        f32x4 x[12];
        #pragma unroll
        for (int jt = 0; jt < 12; jt++)
            x[jt] = __builtin_amdgcn_mfma_f32_16x16x32_f16(Af[jt], Bf, zero4, 0, 0, 0);
        // h-side r,z: C-chained through x
        f32x4 acc[8];
        #pragma unroll
        for (int jt = 0; jt < 8; jt++) {
            f32x4 t0 = __builtin_amdgcn_mfma_f32_16x16x32_f16(Ah[jt][0], Bh0, x[jt], 0, 0, 0);
            acc[jt]  = __builtin_amdgcn_mfma_f32_16x16x32_f16(Ah[jt][1], Bh1, t0, 0, 0, 0);
        }
        // h-side n: C = b_hh(n)
        f32x4 hn[4];
        #pragma unroll
        for (int T = 0; T < 4; T++) {
            f32x4 t0 = __builtin_amdgcn_mfma_f32_16x16x32_f16(Ah[8 + T][0], Bh0, biasH[T], 0, 0, 0);
            hn[T]    = __builtin_amdgcn_mfma_f32_16x16x32_f16(Ah[8 + T][1], Bh1, t0, 0, 0, 0);
        }

        // prefetch Bf(t+1) under the MFMA/activation latency
        half8 BfN;
        {
            const int tn = (t + 1 < TT) ? t + 1 : TT - 1;
            const int p = A.c.pb[tn][8 * w + cr];
            BfN = *(const half8*)&embl[(((p >> sh) & mk) + of) * 8];
            uint4* bu = (uint4*)&BfN;
            bu->z = isu2 ? (((unsigned)p >> 16) | 0x3C000000u) : bu->z;
        }

        // despread: this lane activates tiles (loT ? 0,1 : 2,3) only
        const f32x4 aRA = loT ? acc[0] : acc[2];
        const f32x4 aRB = loT ? acc[1] : acc[3];
        const f32x4 aZA = loT ? acc[4] : acc[6];
        const f32x4 aZB = loT ? acc[5] : acc[7];
        const f32x4 hnA = loT ? hn[0] : hn[2];
        const f32x4 hnB = loT ? hn[1] : hn[3];
        const f32x4 xnA = loT ? x[8] : x[10];
        const f32x4 xnB = loT ? x[9] : x[11];

        const bool live = (t < Ln);
        _Float16 hpA[4], hpB[4];
        #pragma unroll
        for (int e = 0; e < 4; e++) {
            // weights pre-scaled: aR,aZ in log2 domain; xn,hn in 2log2e domain
            {
                const float r = __builtin_amdgcn_rcpf(1.f + __builtin_amdgcn_exp2f(-aRA[e]));
                const float z = __builtin_amdgcn_rcpf(1.f + __builtin_amdgcn_exp2f(-aZA[e]));
                const float y2 = xnA[e] + r * hnA[e];
                const float nn = 1.f - 2.f * __builtin_amdgcn_rcpf(1.f + __builtin_amdgcn_exp2f(y2));
                const float hv = nn + z * (hA[e] - nn);
                hA[e] = live ? hv : hA[e];
                hpA[e] = (_Float16)hA[e];
            }
            {
                const float r = __builtin_amdgcn_rcpf(1.f + __builtin_amdgcn_exp2f(-aRB[e]));
                const float z = __builtin_amdgcn_rcpf(1.f + __builtin_amdgcn_exp2f(-aZB[e]));
                const float y2 = xnB[e] + r * hnB[e];
                const float nn = 1.f - 2.f * __builtin_amdgcn_rcpf(1.f + __builtin_amdgcn_exp2f(y2));
                const float hv = nn + z * (hB[e] - nn);
                hB[e] = live ? hv : hB[e];
                hpB[e] = (_Float16)hB[e];
            }
        }
        // write owned slots: tile T0 at f16 off 16*T0+4u, tile T0+1 at +16
        *(uint2*)&hbW[T0f + 4 * u] = *(uint2*)hpA;
        *(uint2*)&hbW[T0f + 16 + 4 * u] = *(uint2*)hpB;

        Bf = BfN;
    }

    const int row = g * 32 + 8 * w + cr;
    *(float4*)&out[row * HID + T0f + 4 * u] = make_float4(hA[0], hA[1], hA[2], hA[3]);
    *(float4*)&out[row * HID + T0f + 16 + 4 * u] = make_float4(hB[0], hB[1], hB[2], hB[3]);
}

extern "C" void kernel_launch(void* const* d_in, const int* in_sizes, int n_in,
                              void* d_out, int out_size, void* d_ws, size_t ws_size,
                              hipStream_t stream) {
    const int*   actor_ids  = (const int*)d_in[0];
    const int*   action_ids = (const int*)d_in[1];
    const int*   street_ids = (const int*)d_in[2];
    const float* bet        = (const float*)d_in[3];
    const int*   vmask      = (const int*)d_in[4];
    const float* E_actor    = (const float*)d_in[5];
    const float* E_action   = (const float*)d_in[6];
    const float* E_street   = (const float*)d_in[7];
    const float* W_proj     = (const float*)d_in[8];
    const float* b_proj     = (const float*)d_in[9];
    const float* W_ih       = (const float*)d_in[10];
    const float* W_hh       = (const float*)d_in[11];
    const float* b_ih       = (const float*)d_in[12];
    const float* b_hh       = (const float*)d_in[13];
    float*       out        = (float*)d_out;

    gru_fused<<<NBLK, 256, 0, stream>>>(actor_ids, action_ids, street_ids, bet,
                                        vmask, E_actor, E_action, E_street,
                                        W_proj, b_proj, W_ih, b_ih, W_hh, b_hh,
                                        out);
}

// Round 6
// 168.093 us; speedup vs baseline: 1.3049x; 1.3049x over previous
//
#include <hip/hip_runtime.h>

#define HID 64
#define TT  128
#define NROWS 8192
#define NGRP (NROWS / 16)   // 512 blocks of 16 rows; 2 blocks/CU (512 thr each)
#define LOG2E 1.44269504088896f

typedef _Float16 half8 __attribute__((ext_vector_type(8)));
typedef float    f32x4 __attribute__((ext_vector_type(4)));

// ---------- pre-pass: length-sort rows into complementary-paired groups ----------
// ws layout (ints): lens[8192] | perm[8192]

__global__ void k_len(const int* __restrict__ mask, int* __restrict__ lens) {
    const int row = blockIdx.x * 4 + (threadIdx.x >> 6);
    const int l   = threadIdx.x & 63;
    const int* mrow = mask + row * TT;
    int c = (mrow[l] != 0) + (mrow[l + 64] != 0);
    #pragma unroll
    for (int k = 32; k >= 1; k >>= 1) c += __shfl_xor(c, k);
    if (l == 0) lens[row] = c;
}

// Single block: LDS histogram -> LDS prefix -> LDS-atomic scatter.
// Descending length rank d -> group gd = d/16; pair complementary groups so
// blocks b and b+256 (same CU under round-robin dispatch) get ranks k, 511-k.
__global__ __launch_bounds__(1024) void k_sort(const int* __restrict__ lens,
                                               int* __restrict__ perm) {
    __shared__ int hist[TT + 1];
    __shared__ int offs[TT + 1];
    const int tid = threadIdx.x;
    if (tid <= TT) hist[tid] = 0;
    __syncthreads();
    int myL[8];
    #pragma unroll
    for (int i = 0; i < 8; i++) {
        myL[i] = lens[tid + 1024 * i];
        atomicAdd(&hist[myL[i]], 1);
    }
    __syncthreads();
    if (tid <= TT) {
        int s = 0;
        for (int j = 0; j < tid; j++) s += hist[j];
        offs[tid] = s;
    }
    __syncthreads();
    #pragma unroll
    for (int i = 0; i < 8; i++) {
        const int pos = atomicAdd(&offs[myL[i]], 1);      // ascending rank
        const int d   = NROWS - 1 - pos;                  // descending rank
        const int gd  = d >> 4, r = d & 15;
        const int b   = (gd < 256) ? gd : 767 - gd;
        perm[b * 16 + r] = tid + 1024 * i;
    }
}

// ---------- main GRU: 8-wave blocks, wave-PAIRS per j-tile-triple ----------
// Waves 2p, 2p+1 own j-tiles {p, p+4, p+8}; both compute the same 9 MFMAs
// (redundant, cheap) but split activation by acc element: even wave e={0,1},
// odd wave e={2,3}. 2 waves/SIMD on the solo tail block hide chain stalls.
__global__ __launch_bounds__(512, 4) void gru_fused(
    const int* __restrict__ actor_ids, const int* __restrict__ action_ids,
    const int* __restrict__ street_ids, const float* __restrict__ bet,
    const float* __restrict__ E_actor, const float* __restrict__ E_action,
    const float* __restrict__ E_street, const float* __restrict__ W_proj,
    const float* __restrict__ b_proj, const float* __restrict__ W_ih,
    const float* __restrict__ b_ih, const float* __restrict__ W_hh,
    const float* __restrict__ b_hh, const int* __restrict__ perm,
    const int* __restrict__ lens, float* __restrict__ out)
{
    __shared__ __align__(16) union {
        float wfs[192][32];                           // startup: fused W_f (scaled)
        struct {
            int pb[TT][17];                           // ids|bet16, padded
            __align__(16) _Float16 hb[2][16][72];     // h f16 dbuf, stride 72
            int Lsh[16];
            int Psh[16];
        } c;
    } A;
    __shared__ __align__(16) _Float16 embl[144];
    __shared__ float bfs[192];                        // raw fused bias b_f

    const int tid  = threadIdx.x;
    const int wv   = tid >> 6;       // 0..7
    const int p    = wv >> 1;        // j-tile-triple owner pair (0..3)
    const int half = wv & 1;         // activation element half
    const int l    = tid & 63;
    const int q    = l >> 4;         // quad
    const int n    = l & 15;         // batch col within group
    const int g    = blockIdx.x;

    // embedding rows: 0..6 actor, 7..10 action, 11..15 street(+pad), 16 zero
    for (int i = tid; i < 136; i += 512) {
        int r = i >> 3, m = i & 7;
        float v = 0.f;
        if (r < 7)       v = E_actor[r * 8 + m];
        else if (r < 11) v = E_action[(r - 7) * 8 + m];
        else if (r < 16) v = (m < 4) ? E_street[(r - 11) * 4 + m] : 0.f;
        embl[i] = (_Float16)v;
    }

    // ---- startup: fused input weights into LDS ----
    if (tid < 192) {
        const int j = tid;
        float wf[21];
        #pragma unroll
        for (int m = 0; m < 21; m++) wf[m] = 0.f;
        float bf = b_ih[j];
        for (int k = 0; k < 32; k++) {
            const float w = W_ih[j * 32 + k];
            bf += w * b_proj[k];
            #pragma unroll
            for (int m = 0; m < 21; m++) wf[m] += w * W_proj[k * 21 + m];
        }
        const float s = (j < 128) ? LOG2E : 2.f * LOG2E;
        #pragma unroll
        for (int m = 0; m < 21; m++) A.wfs[j][m] = wf[m] * s;
        #pragma unroll
        for (int m = 21; m < 32; m++) A.wfs[j][m] = 0.f;
        bfs[j] = bf;
    }
    __syncthreads();

    // ---- extract per-lane A-fragments + biases (registers) ----
    half8 Af[3], Ah[3][2];
    {
        const int m16 = l & 15, kq = l >> 4;
        #pragma unroll
        for (int g3 = 0; g3 < 3; g3++) {
            const int jr = g3 * 64 + p * 16 + m16;
            _Float16 v[8];
            #pragma unroll
            for (int m = 0; m < 8; m++) v[m] = (_Float16)A.wfs[jr][kq * 8 + m];
            Af[g3] = *(half8*)v;
            const float s = (g3 < 2) ? LOG2E : 2.f * LOG2E;
            #pragma unroll
            for (int kt = 0; kt < 2; kt++) {
                _Float16 w[8];
                #pragma unroll
                for (int m = 0; m < 8; m++)
                    w[m] = (_Float16)(W_hh[jr * HID + kt * 32 + kq * 8 + m] * s);
                Ah[g3][kt] = *(half8*)w;
            }
        }
    }
    f32x4 biasR, biasZ, biasX, biasH;
    #pragma unroll
    for (int e = 0; e < 4; e++) {
        const int idx = 16 * p + 4 * q + e;
        biasR[e] = (bfs[idx]      + b_hh[idx])      * LOG2E;
        biasZ[e] = (bfs[64 + idx] + b_hh[64 + idx]) * LOG2E;
        biasX[e] = bfs[128 + idx]  * (2.f * LOG2E);
        biasH[e] = b_hh[128 + idx] * (2.f * LOG2E);
    }
    __syncthreads();   // wfs dead; arena becomes pb/hb

    // ---- stage pb via perm (32 thr/row), zero hb, fetch lengths ----
    for (int i = tid; i < 2 * 16 * 72 / 2; i += 512) ((int*)A.c.hb)[i] = 0;
    {
        const int r = tid >> 5, tl = tid & 31;
        const int prow = perm[g * 16 + r];
        const int base = prow * TT;
        #pragma unroll
        for (int i = 0; i < 4; i++) {
            const int t = tl + 32 * i;
            const int a = actor_ids[base + t], c = action_ids[base + t];
            const int s = street_ids[base + t];
            const _Float16 f16 = (_Float16)bet[base + t];
            const unsigned fb = (unsigned)*(const unsigned short*)&f16;
            A.c.pb[t][r] = (int)(a | (c << 3) | (s << 5) | (fb << 16));
        }
        if (tl == 0) { A.c.Lsh[r] = lens[prow]; A.c.Psh[r] = prow; }
    }
    __syncthreads();

    const int Ln = A.c.Lsh[n];
    int Lmax = Ln;     // butterfly max over the 16 n-columns (wave-uniform)
    #pragma unroll
    for (int k = 1; k < 16; k <<= 1) {
        const int o = __shfl_xor(Lmax, k);
        Lmax = (o > Lmax) ? o : Lmax;
    }

    const bool isq2 = (q == 2);
    const int sh = (q == 1) ? 3 : (q == 2) ? 5 : 0;
    const int mk = (q == 1) ? 3 : (q == 3) ? 0 : 7;
    const int of = (q == 1) ? 7 : (q == 2) ? 11 : (q == 3) ? 16 : 0;

    // this wave activates elements e = 2*half, 2*half+1 -> j0 = 16p+4q+2half
    const int j0 = 16 * p + 4 * q + 2 * half;
    float h0 = 0.f, h1 = 0.f;
    const f32x4 zero4 = {0.f, 0.f, 0.f, 0.f};

    // ---- x-side software pipeline, 2 steps deep ----
    f32x4 xR, xZ, xX;
    half8 Bfn;
    {
        const int p0 = A.c.pb[0][n];
        const int e0 = ((p0 >> sh) & mk) + of;
        half8 Bf0 = *(const half8*)&embl[e0 * 8];
        uint4* b0 = (uint4*)&Bf0;
        b0->z = isq2 ? ((unsigned)p0 >> 16) : b0->z;   // {bet16, 0} at k=20,21
        xR = __builtin_amdgcn_mfma_f32_16x16x32_f16(Af[0], Bf0, biasR, 0, 0, 0);
        xZ = __builtin_amdgcn_mfma_f32_16x16x32_f16(Af[1], Bf0, biasZ, 0, 0, 0);
        xX = __builtin_amdgcn_mfma_f32_16x16x32_f16(Af[2], Bf0, biasX, 0, 0, 0);

        const int p1 = A.c.pb[1][n];
        const int e1 = ((p1 >> sh) & mk) + of;
        half8 Bf1 = *(const half8*)&embl[e1 * 8];
        uint4* b1 = (uint4*)&Bf1;
        b1->z = isq2 ? ((unsigned)p1 >> 16) : b1->z;
        Bfn = Bf1;
    }

    for (int t = 0; t < Lmax; t++) {
        const int buf = t & 1;
        const half8 Bh0 = *(const half8*)&A.c.hb[buf][n][q * 8];
        const half8 Bh1 = *(const half8*)&A.c.hb[buf][n][32 + q * 8];
        const int t2 = (t + 2 < TT) ? t + 2 : TT - 1;
        const int p2 = A.c.pb[t2][n];

        // h-side MFMAs (R split: two independent + VALU add shortens chain)
        f32x4 aRa = __builtin_amdgcn_mfma_f32_16x16x32_f16(Ah[0][0], Bh0, xR, 0, 0, 0);
        f32x4 aRb = __builtin_amdgcn_mfma_f32_16x16x32_f16(Ah[0][1], Bh1, zero4, 0, 0, 0);
        f32x4 aZ = __builtin_amdgcn_mfma_f32_16x16x32_f16(Ah[1][0], Bh0, xZ, 0, 0, 0);
        aZ = __builtin_amdgcn_mfma_f32_16x16x32_f16(Ah[1][1], Bh1, aZ, 0, 0, 0);
        f32x4 aH = __builtin_amdgcn_mfma_f32_16x16x32_f16(Ah[2][0], Bh0, biasH, 0, 0, 0);
        aH = __builtin_amdgcn_mfma_f32_16x16x32_f16(Ah[2][1], Bh1, aH, 0, 0, 0);
        const f32x4 aR = aRa + aRb;
        const f32x4 aXc = xX;

        // x-side MFMAs for t+1: pure-register B operand
        const f32x4 xRn = __builtin_amdgcn_mfma_f32_16x16x32_f16(Af[0], Bfn, biasR, 0, 0, 0);
        const f32x4 xZn = __builtin_amdgcn_mfma_f32_16x16x32_f16(Af[1], Bfn, biasZ, 0, 0, 0);
        const f32x4 xXn = __builtin_amdgcn_mfma_f32_16x16x32_f16(Af[2], Bfn, biasX, 0, 0, 0);

        // gather Bf(t+2); latency hides under the activation
        half8 Bf2;
        {
            const int e2 = ((p2 >> sh) & mk) + of;
            Bf2 = *(const half8*)&embl[e2 * 8];
            uint4* b2 = (uint4*)&Bf2;
            b2->z = isq2 ? ((unsigned)p2 >> 16) : b2->z;
        }

        // activation: this wave's 2 elements only (static halving of trans issue)
        const float vR0 = half ? aR[2]  : aR[0],  vR1 = half ? aR[3]  : aR[1];
        const float vZ0 = half ? aZ[2]  : aZ[0],  vZ1 = half ? aZ[3]  : aZ[1];
        const float vH0 = half ? aH[2]  : aH[0],  vH1 = half ? aH[3]  : aH[1];
        const float vX0 = half ? aXc[2] : aXc[0], vX1 = half ? aXc[3] : aXc[1];

        const bool live = (t < Ln);
        {
            const float r0 = __builtin_amdgcn_rcpf(1.f + __builtin_amdgcn_exp2f(-vR0));
            const float z0 = __builtin_amdgcn_rcpf(1.f + __builtin_amdgcn_exp2f(-vZ0));
            const float y0 = vX0 + r0 * vH0;
            const float n0 = 1.f - 2.f * __builtin_amdgcn_rcpf(1.f + __builtin_amdgcn_exp2f(y0));
            const float hv0 = n0 + z0 * (h0 - n0);
            h0 = live ? hv0 : h0;

            const float r1 = __builtin_amdgcn_rcpf(1.f + __builtin_amdgcn_exp2f(-vR1));
            const float z1 = __builtin_amdgcn_rcpf(1.f + __builtin_amdgcn_exp2f(-vZ1));
            const float y1 = vX1 + r1 * vH1;
            const float n1 = 1.f - 2.f * __builtin_amdgcn_rcpf(1.f + __builtin_amdgcn_exp2f(y1));
            const float hv1 = n1 + z1 * (h1 - n1);
            h1 = live ? hv1 : h1;
        }
        // pack 2 f16 -> one b32 write at [n][j0]
        {
            const _Float16 a16 = (_Float16)h0, b16 = (_Float16)h1;
            const unsigned pk = (unsigned)*(const unsigned short*)&a16 |
                                ((unsigned)*(const unsigned short*)&b16 << 16);
            *(unsigned*)&A.c.hb[buf ^ 1][n][j0] = pk;
        }
        __syncthreads();

        xR = xRn; xZ = xZn; xX = xXn; Bfn = Bf2;
    }

    const int prow = A.c.Psh[n];
    *(float2*)&out[prow * HID + j0] = make_float2(h0, h1);
}

extern "C" void kernel_launch(void* const* d_in, const int* in_sizes, int n_in,
                              void* d_out, int out_size, void* d_ws, size_t ws_size,
                              hipStream_t stream) {
    const int*   actor_ids  = (const int*)d_in[0];
    const int*   action_ids = (const int*)d_in[1];
    const int*   street_ids = (const int*)d_in[2];
    const float* bet        = (const float*)d_in[3];
    const int*   vmask      = (const int*)d_in[4];
    const float* E_actor    = (const float*)d_in[5];
    const float* E_action   = (const float*)d_in[6];
    const float* E_street   = (const float*)d_in[7];
    const float* W_proj     = (const float*)d_in[8];
    const float* b_proj     = (const float*)d_in[9];
    const float* W_ih       = (const float*)d_in[10];
    const float* W_hh       = (const float*)d_in[11];
    const float* b_ih       = (const float*)d_in[12];
    const float* b_hh       = (const float*)d_in[13];
    float*       out        = (float*)d_out;

    int* ws   = (int*)d_ws;
    int* lens = ws;
    int* perm = ws + NROWS;

    k_len<<<NROWS / 4, 256, 0, stream>>>(vmask, lens);
    k_sort<<<1, 1024, 0, stream>>>(lens, perm);

    gru_fused<<<NGRP, 512, 0, stream>>>(actor_ids, action_ids, street_ids, bet,
                                        E_actor, E_action, E_street,
                                        W_proj, b_proj, W_ih, b_ih, W_hh, b_hh,
                                        perm, lens, out);
}

// Round 7
// 164.597 us; speedup vs baseline: 1.3326x; 1.0212x over previous
//
#include <hip/hip_runtime.h>

#define HID 64
#define TT  128
#define NROWS 8192
#define NGRP (NROWS / 8)    // 1024 blocks of 8 rows; 4 blocks/CU
#define LOG2E 1.44269504088896f

typedef _Float16 half8 __attribute__((ext_vector_type(8)));
typedef float    f32x4 __attribute__((ext_vector_type(4)));

// ---------- pre-pass: length-sort rows into balanced 8-row groups ----------
// ws layout (ints): lens[8192] | perm[8192]

__global__ void k_len(const int* __restrict__ mask, int* __restrict__ lens) {
    const int row = blockIdx.x * 4 + (threadIdx.x >> 6);
    const int l   = threadIdx.x & 63;
    const int* mrow = mask + row * TT;
    int c = (mrow[l] != 0) + (mrow[l + 64] != 0);
    #pragma unroll
    for (int k = 32; k >= 1; k >>= 1) c += __shfl_xor(c, k);
    if (l == 0) lens[row] = c;
}

// Single block: LDS histogram -> prefix -> scatter. Descending rank d ->
// 8-row group g8 = d/8. Slot map puts ranks {c, 511-c, 512+c, 1023-c} on
// CU c (round-robin dispatch assumption): per-CU work ~balanced, tail CU
// holds the single 128-step group plus ~64+64+0.
__global__ __launch_bounds__(1024) void k_sort(const int* __restrict__ lens,
                                               int* __restrict__ perm) {
    __shared__ int hist[TT + 1];
    __shared__ int offs[TT + 1];
    const int tid = threadIdx.x;
    if (tid <= TT) hist[tid] = 0;
    __syncthreads();
    int myL[8];
    #pragma unroll
    for (int i = 0; i < 8; i++) {
        myL[i] = lens[tid + 1024 * i];
        atomicAdd(&hist[myL[i]], 1);
    }
    __syncthreads();
    if (tid <= TT) {
        int s = 0;
        for (int j = 0; j < tid; j++) s += hist[j];
        offs[tid] = s;
    }
    __syncthreads();
    #pragma unroll
    for (int i = 0; i < 8; i++) {
        const int pos = atomicAdd(&offs[myL[i]], 1);      // ascending rank
        const int d   = NROWS - 1 - pos;                  // descending rank
        const int g8  = d >> 3, r = d & 7;
        int b;
        if      (g8 < 256) b = g8;                 // slot0: CU g8
        else if (g8 < 512) b = 256 + (511 - g8);   // slot1: CU 511-g8
        else if (g8 < 768) b = 512 + (g8 - 512);   // slot2: CU g8-512
        else               b = 768 + (1023 - g8);  // slot3: CU 1023-g8
        perm[b * 8 + r] = tid + 1024 * i;
    }
}

// ---------- main GRU: 8-row blocks, col-duplicated MFMA, half-split act ----------
// Cols 0-7 = rows, cols 8-15 = duplicates. Lane cc<8 activates e={0,1},
// cc>=8 activates e={2,3} of the same row -> 12 trans/wave-step (vs 24).
__global__ __launch_bounds__(256, 4) void gru_fused(
    const int* __restrict__ actor_ids, const int* __restrict__ action_ids,
    const int* __restrict__ street_ids, const float* __restrict__ bet,
    const float* __restrict__ E_actor, const float* __restrict__ E_action,
    const float* __restrict__ E_street, const float* __restrict__ W_proj,
    const float* __restrict__ b_proj, const float* __restrict__ W_ih,
    const float* __restrict__ b_ih, const float* __restrict__ W_hh,
    const float* __restrict__ b_hh, const int* __restrict__ perm,
    const int* __restrict__ lens, float* __restrict__ out)
{
    __shared__ __align__(16) union {
        float wfs[192][32];                           // startup: fused W_f (scaled)
        struct {
            int pb[TT][9];                            // ids|bet16, 8 rows + pad
            __align__(16) _Float16 hb[2][8][72];      // h f16 dbuf, stride 72
            int Lsh[8];
            int Psh[8];
        } c;
    } A;
    __shared__ __align__(16) _Float16 embl[144];
    __shared__ float bfs[192];                        // raw fused bias b_f

    const int tid = threadIdx.x;
    const int wv  = tid >> 6;        // wave = hid quarter (j-split)
    const int l   = tid & 63;
    const int q   = l >> 4;          // k-quad / j-subquad
    const int cc  = l & 15;          // MFMA col
    const int cr  = cc & 7;          // batch row within group
    const int hf  = cc >> 3;         // activation element half
    const int g   = blockIdx.x;

    // embedding rows: 0..6 actor, 7..10 action, 11..15 street(+pad), 16 zero
    for (int i = tid; i < 136; i += 256) {
        int r = i >> 3, m = i & 7;
        float v = 0.f;
        if (r < 7)       v = E_actor[r * 8 + m];
        else if (r < 11) v = E_action[(r - 7) * 8 + m];
        else if (r < 16) v = (m < 4) ? E_street[(r - 11) * 4 + m] : 0.f;
        embl[i] = (_Float16)v;
    }

    // ---- startup: fused input weights into LDS ----
    if (tid < 192) {
        const int j = tid;
        float wf[21];
        #pragma unroll
        for (int m = 0; m < 21; m++) wf[m] = 0.f;
        float bf = b_ih[j];
        for (int k = 0; k < 32; k++) {
            const float w = W_ih[j * 32 + k];
            bf += w * b_proj[k];
            #pragma unroll
            for (int m = 0; m < 21; m++) wf[m] += w * W_proj[k * 21 + m];
        }
        const float s = (j < 128) ? LOG2E : 2.f * LOG2E;
        #pragma unroll
        for (int m = 0; m < 21; m++) A.wfs[j][m] = wf[m] * s;
        #pragma unroll
        for (int m = 21; m < 32; m++) A.wfs[j][m] = 0.f;
        bfs[j] = bf;
    }
    __syncthreads();

    // ---- extract per-lane A-fragments + biases (registers) ----
    half8 Af[3], Ah[3][2];
    {
        const int m16 = l & 15, kq = l >> 4;
        #pragma unroll
        for (int g3 = 0; g3 < 3; g3++) {
            const int jr = g3 * 64 + wv * 16 + m16;
            _Float16 v[8];
            #pragma unroll
            for (int m = 0; m < 8; m++) v[m] = (_Float16)A.wfs[jr][kq * 8 + m];
            Af[g3] = *(half8*)v;
            const float s = (g3 < 2) ? LOG2E : 2.f * LOG2E;
            #pragma unroll
            for (int kt = 0; kt < 2; kt++) {
                _Float16 w[8];
                #pragma unroll
                for (int m = 0; m < 8; m++)
                    w[m] = (_Float16)(W_hh[jr * HID + kt * 32 + kq * 8 + m] * s);
                Ah[g3][kt] = *(half8*)w;
            }
        }
    }
    f32x4 biasR, biasZ, biasX, biasH;
    #pragma unroll
    for (int e = 0; e < 4; e++) {
        const int idx = 16 * wv + 4 * q + e;
        biasR[e] = (bfs[idx]      + b_hh[idx])      * LOG2E;
        biasZ[e] = (bfs[64 + idx] + b_hh[64 + idx]) * LOG2E;
        biasX[e] = bfs[128 + idx]  * (2.f * LOG2E);
        biasH[e] = b_hh[128 + idx] * (2.f * LOG2E);
    }
    __syncthreads();   // wfs dead; arena becomes pb/hb

    // ---- stage pb via perm (32 thr/row), zero hb, fetch lengths ----
    for (int i = tid; i < 2 * 8 * 72 / 2; i += 256) ((int*)A.c.hb)[i] = 0;
    {
        const int r = tid >> 5, tl = tid & 31;
        const int prow = perm[g * 8 + r];
        const int base = prow * TT;
        #pragma unroll
        for (int i = 0; i < 4; i++) {
            const int t = tl + 32 * i;
            const int a = actor_ids[base + t], c = action_ids[base + t];
            const int s = street_ids[base + t];
            const _Float16 f16 = (_Float16)bet[base + t];
            const unsigned fb = (unsigned)*(const unsigned short*)&f16;
            A.c.pb[t][r] = (int)(a | (c << 3) | (s << 5) | (fb << 16));
        }
        if (tl == 0) { A.c.Lsh[r] = lens[prow]; A.c.Psh[r] = prow; }
    }
    __syncthreads();

    const int Ln = A.c.Lsh[cr];
    int Lmax = Ln;     // max over the 8 rows (xor 1,2,4 covers cr 0..7)
    { int o = __shfl_xor(Lmax, 1); Lmax = o > Lmax ? o : Lmax; }
    { int o = __shfl_xor(Lmax, 2); Lmax = o > Lmax ? o : Lmax; }
    { int o = __shfl_xor(Lmax, 4); Lmax = o > Lmax ? o : Lmax; }

    const bool isq2 = (q == 2);
    const int sh = (q == 1) ? 3 : (q == 2) ? 5 : 0;
    const int mk = (q == 1) ? 3 : (q == 3) ? 0 : 7;
    const int of = (q == 1) ? 7 : (q == 2) ? 11 : (q == 3) ? 16 : 0;

    // this lane activates elements e = 2*hf, 2*hf+1 -> j0 = 16wv+4q+2hf
    const int j0 = 16 * wv + 4 * q + 2 * hf;
    float h0 = 0.f, h1 = 0.f;
    const f32x4 zero4 = {0.f, 0.f, 0.f, 0.f};

    // ---- x-side software pipeline, 2 steps deep ----
    f32x4 xR, xZ, xX;
    half8 Bfn;
    {
        const int p0 = A.c.pb[0][cr];
        const int e0 = ((p0 >> sh) & mk) + of;
        half8 Bf0 = *(const half8*)&embl[e0 * 8];
        uint4* b0 = (uint4*)&Bf0;
        b0->z = isq2 ? ((unsigned)p0 >> 16) : b0->z;   // {bet16, 0} at k=20,21
        xR = __builtin_amdgcn_mfma_f32_16x16x32_f16(Af[0], Bf0, biasR, 0, 0, 0);
        xZ = __builtin_amdgcn_mfma_f32_16x16x32_f16(Af[1], Bf0, biasZ, 0, 0, 0);
        xX = __builtin_amdgcn_mfma_f32_16x16x32_f16(Af[2], Bf0, biasX, 0, 0, 0);

        const int p1 = A.c.pb[1][cr];
        const int e1 = ((p1 >> sh) & mk) + of;
        half8 Bf1 = *(const half8*)&embl[e1 * 8];
        uint4* b1 = (uint4*)&Bf1;
        b1->z = isq2 ? ((unsigned)p1 >> 16) : b1->z;
        Bfn = Bf1;
    }

    for (int t = 0; t < Lmax; t++) {
        const int buf = t & 1;
        const half8 Bh0 = *(const half8*)&A.c.hb[buf][cr][q * 8];
        const half8 Bh1 = *(const half8*)&A.c.hb[buf][cr][32 + q * 8];
        const int t2 = (t + 2 < TT) ? t + 2 : TT - 1;
        const int p2 = A.c.pb[t2][cr];

        // h-side MFMAs (R split: two independent + VALU add shortens chain)
        f32x4 aRa = __builtin_amdgcn_mfma_f32_16x16x32_f16(Ah[0][0], Bh0, xR, 0, 0, 0);
        f32x4 aRb = __builtin_amdgcn_mfma_f32_16x16x32_f16(Ah[0][1], Bh1, zero4, 0, 0, 0);
        f32x4 aZ = __builtin_amdgcn_mfma_f32_16x16x32_f16(Ah[1][0], Bh0, xZ, 0, 0, 0);
        aZ = __builtin_amdgcn_mfma_f32_16x16x32_f16(Ah[1][1], Bh1, aZ, 0, 0, 0);
        f32x4 aH = __builtin_amdgcn_mfma_f32_16x16x32_f16(Ah[2][0], Bh0, biasH, 0, 0, 0);
        aH = __builtin_amdgcn_mfma_f32_16x16x32_f16(Ah[2][1], Bh1, aH, 0, 0, 0);
        const f32x4 aR = aRa + aRb;
        const f32x4 aXc = xX;

        // x-side MFMAs for t+1: pure-register B operand
        const f32x4 xRn = __builtin_amdgcn_mfma_f32_16x16x32_f16(Af[0], Bfn, biasR, 0, 0, 0);
        const f32x4 xZn = __builtin_amdgcn_mfma_f32_16x16x32_f16(Af[1], Bfn, biasZ, 0, 0, 0);
        const f32x4 xXn = __builtin_amdgcn_mfma_f32_16x16x32_f16(Af[2], Bfn, biasX, 0, 0, 0);

        // gather Bf(t+2); latency hides under the activation
        half8 Bf2;
        {
            const int e2 = ((p2 >> sh) & mk) + of;
            Bf2 = *(const half8*)&embl[e2 * 8];
            uint4* b2 = (uint4*)&Bf2;
            b2->z = isq2 ? ((unsigned)p2 >> 16) : b2->z;
        }

        // activation: this lane's 2 elements only (per-wave trans halved)
        const float vR0 = hf ? aR[2]  : aR[0],  vR1 = hf ? aR[3]  : aR[1];
        const float vZ0 = hf ? aZ[2]  : aZ[0],  vZ1 = hf ? aZ[3]  : aZ[1];
        const float vH0 = hf ? aH[2]  : aH[0],  vH1 = hf ? aH[3]  : aH[1];
        const float vX0 = hf ? aXc[2] : aXc[0], vX1 = hf ? aXc[3] : aXc[1];

        const bool live = (t < Ln);
        {
            const float r0 = __builtin_amdgcn_rcpf(1.f + __builtin_amdgcn_exp2f(-vR0));
            const float z0 = __builtin_amdgcn_rcpf(1.f + __builtin_amdgcn_exp2f(-vZ0));
            const float y0 = vX0 + r0 * vH0;
            const float n0 = 1.f - 2.f * __builtin_amdgcn_rcpf(1.f + __builtin_amdgcn_exp2f(y0));
            const float hv0 = n0 + z0 * (h0 - n0);
            h0 = live ? hv0 : h0;

            const float r1 = __builtin_amdgcn_rcpf(1.f + __builtin_amdgcn_exp2f(-vR1));
            const float z1 = __builtin_amdgcn_rcpf(1.f + __builtin_amdgcn_exp2f(-vZ1));
            const float y1 = vX1 + r1 * vH1;
            const float n1 = 1.f - 2.f * __builtin_amdgcn_rcpf(1.f + __builtin_amdgcn_exp2f(y1));
            const float hv1 = n1 + z1 * (h1 - n1);
            h1 = live ? hv1 : h1;
        }
        // pack 2 f16 -> one b32 write at [cr][j0]
        {
            const _Float16 a16 = (_Float16)h0, b16 = (_Float16)h1;
            const unsigned pk = (unsigned)*(const unsigned short*)&a16 |
                                ((unsigned)*(const unsigned short*)&b16 << 16);
            *(unsigned*)&A.c.hb[buf ^ 1][cr][j0] = pk;
        }
        __syncthreads();

        xR = xRn; xZ = xZn; xX = xXn; Bfn = Bf2;
    }

    const int prow = A.c.Psh[cr];
    *(float2*)&out[prow * HID + j0] = make_float2(h0, h1);
}

extern "C" void kernel_launch(void* const* d_in, const int* in_sizes, int n_in,
                              void* d_out, int out_size, void* d_ws, size_t ws_size,
                              hipStream_t stream) {
    const int*   actor_ids  = (const int*)d_in[0];
    const int*   action_ids = (const int*)d_in[1];
    const int*   street_ids = (const int*)d_in[2];
    const float* bet        = (const float*)d_in[3];
    const int*   vmask      = (const int*)d_in[4];
    const float* E_actor    = (const float*)d_in[5];
    const float* E_action   = (const float*)d_in[6];
    const float* E_street   = (const float*)d_in[7];
    const float* W_proj     = (const float*)d_in[8];
    const float* b_proj     = (const float*)d_in[9];
    const float* W_ih       = (const float*)d_in[10];
    const float* W_hh       = (const float*)d_in[11];
    const float* b_ih       = (const float*)d_in[12];
    const float* b_hh       = (const float*)d_in[13];
    float*       out        = (float*)d_out;

    int* ws   = (int*)d_ws;
    int* lens = ws;
    int* perm = ws + NROWS;

    k_len<<<NROWS / 4, 256, 0, stream>>>(vmask, lens);
    k_sort<<<1, 1024, 0, stream>>>(lens, perm);

    gru_fused<<<NGRP, 256, 0, stream>>>(actor_ids, action_ids, street_ids, bet,
                                        E_actor, E_action, E_street,
                                        W_proj, b_proj, W_ih, b_ih, W_hh, b_hh,
                                        perm, lens, out);
}